// Round 2
// baseline (392.513 us; speedup 1.0000x reference)
//
#include <hip/hip_runtime.h>

#define NSEQ 2048
#define CDIM 768
#define NBATCH 4
#define NHEAD 12
#define HD 64
#define MTOT (NBATCH * NSEQ)   // 8192
#define NQKV (3 * CDIM)        // 2304

typedef float f32x4 __attribute__((ext_vector_type(4)));
typedef short bf16x8 __attribute__((ext_vector_type(8)));

__device__ __forceinline__ short f2bf(float f) {
  union { float f; unsigned u; } x; x.f = f;
  unsigned r = x.u + 0x7fffu + ((x.u >> 16) & 1u);   // RNE
  return (short)(r >> 16);
}

// ---------------- mask dtype detection (bool may arrive as u8 / i32 / f32) ----
__global__ __launch_bounds__(256) void detect_mask(const unsigned char* __restrict__ m,
                                                   int* __restrict__ flag) {
  __shared__ int f1, f23;
  if (threadIdx.x == 0) { f1 = 0; f23 = 0; }
  __syncthreads();
  int a = 0, b = 0;
  for (int i = threadIdx.x; i < 1024; i += 256) {
    if (m[i * 4 + 1]) a = 1;                       // nonzero here => 1-byte elements
    if (m[i * 4 + 2] | m[i * 4 + 3]) b = 1;        // nonzero here => f32 (0x3F800000) or u8
  }
  if (a) atomicOr(&f1, 1);
  if (b) atomicOr(&f23, 1);
  __syncthreads();
  if (threadIdx.x == 0) *flag = f1 ? 1 : (f23 ? 2 : 0);  // 1=u8, 2=f32, 0=i32
}

// ---------------- pack mask into bits: word w bit j = mask[w*32+j] -----------
__global__ __launch_bounds__(256) void pack_mask(const void* __restrict__ mask,
                                                 const int* __restrict__ flag,
                                                 unsigned* __restrict__ bits) {
  int wi = blockIdx.x * 256 + threadIdx.x;   // 0..131071
  int f = *flag;
  unsigned v = 0;
  if (f == 1) {
    const unsigned char* p = (const unsigned char*)mask + (size_t)wi * 32;
#pragma unroll
    for (int j = 0; j < 32; ++j) v |= (p[j] != 0 ? 1u : 0u) << j;
  } else if (f == 2) {
    const float* p = (const float*)mask + (size_t)wi * 32;
#pragma unroll
    for (int j = 0; j < 32; ++j) v |= (p[j] != 0.f ? 1u : 0u) << j;
  } else {
    const int* p = (const int*)mask + (size_t)wi * 32;
#pragma unroll
    for (int j = 0; j < 32; ++j) v |= (p[j] != 0 ? 1u : 0u) << j;
  }
  bits[wi] = v;
}

// ---------------- fp32 -> bf16 bulk convert (8 elems/thread) -----------------
__global__ __launch_bounds__(256) void conv_bf16(const float* __restrict__ in,
                                                 short* __restrict__ out, int n) {
  int i = (blockIdx.x * 256 + threadIdx.x) * 8;
  if (i >= n) return;
  f32x4 a = *(const f32x4*)&in[i];
  f32x4 b = *(const f32x4*)&in[i + 4];
  bf16x8 o;
#pragma unroll
  for (int j = 0; j < 4; ++j) o[j] = f2bf(a[j]);
#pragma unroll
  for (int j = 0; j < 4; ++j) o[4 + j] = f2bf(b[j]);
  *(bf16x8*)&out[i] = o;
}

// ---------------- transpose + convert: in fp32 [R][Cc] -> out bf16 [Cc][R] ---
__global__ __launch_bounds__(256) void transpose_conv(const float* __restrict__ in,
                                                      short* __restrict__ outp,
                                                      int R, int Cc) {
  __shared__ short tile[64][65];
  int c0 = blockIdx.x * 64, r0 = blockIdx.y * 64;
  int t = threadIdx.x;
  int tr = t >> 4;           // 0..15
  int tc = (t & 15) * 4;     // 0..60
  for (int rr = tr; rr < 64; rr += 16) {
    f32x4 v = *(const f32x4*)&in[(size_t)(r0 + rr) * Cc + c0 + tc];
#pragma unroll
    for (int j = 0; j < 4; ++j) tile[tc + j][rr] = f2bf(v[j]);
  }
  __syncthreads();
  for (int cc = tr; cc < 64; cc += 16) {
#pragma unroll
    for (int j = 0; j < 4; ++j)
      outp[(size_t)(c0 + cc) * R + r0 + tc + j] = tile[cc][tc + j];
  }
}

// ---------------- bf16 GEMM: C[M,N] = A[M,K] * Bt[N,K]^T (+bias, f32 out) ----
// 128x128 tile, BK=32, 4 waves of 64x64, mfma_f32_16x16x32_bf16
template <bool F32OUT>
__global__ __launch_bounds__(256) void gemm_bt(const short* __restrict__ A,
                                               const short* __restrict__ Bt,
                                               void* __restrict__ Cout,
                                               const float* __restrict__ bias,
                                               int Mdim, int Ndim, int Kdim) {
  __shared__ short As[128][40];
  __shared__ short Bs[128][40];
  const int tid = threadIdx.x;
  const int lane = tid & 63;
  const int w = tid >> 6;
  const int wm = (w >> 1) * 64, wn = (w & 1) * 64;
  const int lr = lane & 15, lh = lane >> 4;
  const int m0 = blockIdx.y * 128, n0 = blockIdx.x * 128;
  const int sr = tid >> 2;          // 0..63
  const int sk = (tid & 3) * 8;     // 0,8,16,24

  f32x4 acc[4][4];
#pragma unroll
  for (int i = 0; i < 4; ++i)
#pragma unroll
    for (int j = 0; j < 4; ++j) acc[i][j] = (f32x4){0.f, 0.f, 0.f, 0.f};

  const short* Ar0 = A + (size_t)(m0 + sr) * Kdim + sk;
  const short* Ar1 = A + (size_t)(m0 + sr + 64) * Kdim + sk;
  const short* Br0 = Bt + (size_t)(n0 + sr) * Kdim + sk;
  const short* Br1 = Bt + (size_t)(n0 + sr + 64) * Kdim + sk;

  for (int k0 = 0; k0 < Kdim; k0 += 32) {
    __syncthreads();
    *(bf16x8*)&As[sr][sk]      = *(const bf16x8*)(Ar0 + k0);
    *(bf16x8*)&As[sr + 64][sk] = *(const bf16x8*)(Ar1 + k0);
    *(bf16x8*)&Bs[sr][sk]      = *(const bf16x8*)(Br0 + k0);
    *(bf16x8*)&Bs[sr + 64][sk] = *(const bf16x8*)(Br1 + k0);
    __syncthreads();
    bf16x8 a[4], b[4];
#pragma unroll
    for (int i = 0; i < 4; ++i) a[i] = *(const bf16x8*)&As[wm + i * 16 + lr][lh * 8];
#pragma unroll
    for (int j = 0; j < 4; ++j) b[j] = *(const bf16x8*)&Bs[wn + j * 16 + lr][lh * 8];
#pragma unroll
    for (int i = 0; i < 4; ++i)
#pragma unroll
      for (int j = 0; j < 4; ++j)
        acc[i][j] = __builtin_amdgcn_mfma_f32_16x16x32_bf16(a[i], b[j], acc[i][j], 0, 0, 0);
  }

#pragma unroll
  for (int i = 0; i < 4; ++i) {
    int mrowb = m0 + wm + i * 16 + lh * 4;
#pragma unroll
    for (int j = 0; j < 4; ++j) {
      int ncol = n0 + wn + j * 16 + lr;
#pragma unroll
      for (int r = 0; r < 4; ++r) {
        float v = acc[i][j][r];
        if (F32OUT)
          ((float*)Cout)[(size_t)(mrowb + r) * Ndim + ncol] = v + bias[ncol];
        else
          ((short*)Cout)[(size_t)(mrowb + r) * Ndim + ncol] = f2bf(v);
      }
    }
  }
}

// ---------------- flash attention: QBLK=64 (4 waves x 16 rows), KVBLK=64 -----
__global__ __launch_bounds__(256) void flash_attn(const short* __restrict__ qkv, // [8192][2304]
                                                  const unsigned long long* __restrict__ mbits, // [2048][32]
                                                  short* __restrict__ outp) {    // [8192][768]
  __shared__ short Qs[64][72];
  __shared__ short Ks[64][72];
  __shared__ short Vt[64][72];        // Vt[d][kv]
  __shared__ short Ps[4][16][72];     // per-wave P tile

  const int tid = threadIdx.x;
  const int lane = tid & 63;
  const int w = tid >> 6;
  const int lr = lane & 15, lh = lane >> 4;
  const int q0 = blockIdx.x * 64;
  const int bh = blockIdx.y;
  const int b = bh / NHEAD, h = bh % NHEAD;
  const int sr = tid >> 2;        // 0..63
  const int sd = (tid & 3) * 8;   // 0,8,16,24

  {
    const short* qrow = qkv + (size_t)(b * NSEQ + q0 + sr) * NQKV + h * HD;
    *(bf16x8*)&Qs[sr][sd]      = *(const bf16x8*)(qrow + sd);
    *(bf16x8*)&Qs[sr][sd + 32] = *(const bf16x8*)(qrow + sd + 32);
  }
  __syncthreads();
  bf16x8 qf[2];
  qf[0] = *(const bf16x8*)&Qs[w * 16 + lr][lh * 8];
  qf[1] = *(const bf16x8*)&Qs[w * 16 + lr][32 + lh * 8];

  float m_r[4], l_r[4];
  f32x4 o[4];
#pragma unroll
  for (int r = 0; r < 4; ++r) { m_r[r] = -1e30f; l_r[r] = 0.f; }
#pragma unroll
  for (int d = 0; d < 4; ++d) o[d] = (f32x4){0.f, 0.f, 0.f, 0.f};

  for (int kv0 = 0; kv0 < NSEQ; kv0 += 64) {
    const short* krow = qkv + (size_t)(b * NSEQ + kv0 + sr) * NQKV + CDIM + h * HD;
    bf16x8 kv0v = *(const bf16x8*)(krow + sd);
    bf16x8 kv1v = *(const bf16x8*)(krow + sd + 32);
    bf16x8 vv0  = *(const bf16x8*)(krow + CDIM + sd);
    bf16x8 vv1  = *(const bf16x8*)(krow + CDIM + sd + 32);
    __syncthreads();   // previous tile's compute done
    *(bf16x8*)&Ks[sr][sd]      = kv0v;
    *(bf16x8*)&Ks[sr][sd + 32] = kv1v;
#pragma unroll
    for (int j = 0; j < 8; ++j) Vt[sd + j][sr] = vv0[j];
#pragma unroll
    for (int j = 0; j < 8; ++j) Vt[sd + 32 + j][sr] = vv1[j];
    __syncthreads();

    // S = (Q K^T) * scale, masked
    f32x4 s[4];
#pragma unroll
    for (int nb = 0; nb < 4; ++nb) {
      bf16x8 kf0 = *(const bf16x8*)&Ks[nb * 16 + lr][lh * 8];
      bf16x8 kf1 = *(const bf16x8*)&Ks[nb * 16 + lr][32 + lh * 8];
      f32x4 z = (f32x4){0.f, 0.f, 0.f, 0.f};
      z = __builtin_amdgcn_mfma_f32_16x16x32_bf16(qf[0], kf0, z, 0, 0, 0);
      z = __builtin_amdgcn_mfma_f32_16x16x32_bf16(qf[1], kf1, z, 0, 0, 0);
      s[nb] = z;
    }
    unsigned long long mw[4];
#pragma unroll
    for (int r = 0; r < 4; ++r)
      mw[r] = mbits[(size_t)(q0 + w * 16 + lh * 4 + r) * (NSEQ / 64) + (kv0 >> 6)];
#pragma unroll
    for (int nb = 0; nb < 4; ++nb)
#pragma unroll
      for (int r = 0; r < 4; ++r) {
        float sv = s[nb][r] * 0.125f;
        if ((mw[r] >> (nb * 16 + lr)) & 1ull) sv = -1e30f;
        s[nb][r] = sv;
      }

    // online softmax (rows live in 16-lane groups)
    float pmax[4];
#pragma unroll
    for (int r = 0; r < 4; ++r)
      pmax[r] = fmaxf(fmaxf(s[0][r], s[1][r]), fmaxf(s[2][r], s[3][r]));
#pragma unroll
    for (int off = 1; off <= 8; off <<= 1)
#pragma unroll
      for (int r = 0; r < 4; ++r) pmax[r] = fmaxf(pmax[r], __shfl_xor(pmax[r], off, 64));
    float alpha[4];
#pragma unroll
    for (int r = 0; r < 4; ++r) {
      float nm = fmaxf(m_r[r], pmax[r]);
      alpha[r] = __expf(m_r[r] - nm);
      m_r[r] = nm;
    }
    float rs[4] = {0.f, 0.f, 0.f, 0.f};
#pragma unroll
    for (int nb = 0; nb < 4; ++nb)
#pragma unroll
      for (int r = 0; r < 4; ++r) {
        float p = __expf(s[nb][r] - m_r[r]);
        s[nb][r] = p;
        rs[r] += p;
      }
#pragma unroll
    for (int off = 1; off <= 8; off <<= 1)
#pragma unroll
      for (int r = 0; r < 4; ++r) rs[r] += __shfl_xor(rs[r], off, 64);
#pragma unroll
    for (int r = 0; r < 4; ++r) l_r[r] = l_r[r] * alpha[r] + rs[r];
#pragma unroll
    for (int d = 0; d < 4; ++d)
#pragma unroll
      for (int r = 0; r < 4; ++r) o[d][r] *= alpha[r];

    // P -> LDS (C-layout) then reread as A-fragments
#pragma unroll
    for (int nb = 0; nb < 4; ++nb)
#pragma unroll
      for (int r = 0; r < 4; ++r) Ps[w][lh * 4 + r][nb * 16 + lr] = f2bf(s[nb][r]);
    bf16x8 pa0 = *(const bf16x8*)&Ps[w][lr][lh * 8];
    bf16x8 pa1 = *(const bf16x8*)&Ps[w][lr][32 + lh * 8];
#pragma unroll
    for (int nd = 0; nd < 4; ++nd) {
      bf16x8 vf0 = *(const bf16x8*)&Vt[nd * 16 + lr][lh * 8];
      bf16x8 vf1 = *(const bf16x8*)&Vt[nd * 16 + lr][32 + lh * 8];
      o[nd] = __builtin_amdgcn_mfma_f32_16x16x32_bf16(pa0, vf0, o[nd], 0, 0, 0);
      o[nd] = __builtin_amdgcn_mfma_f32_16x16x32_bf16(pa1, vf1, o[nd], 0, 0, 0);
    }
  }

#pragma unroll
  for (int nd = 0; nd < 4; ++nd)
#pragma unroll
    for (int r = 0; r < 4; ++r) {
      int qr = q0 + w * 16 + lh * 4 + r;
      outp[(size_t)(b * NSEQ + qr) * CDIM + h * HD + nd * 16 + lr] = f2bf(o[nd][r] / l_r[r]);
    }
}

// ---------------- launch --------------------------------------------------
extern "C" void kernel_launch(void* const* d_in, const int* in_sizes, int n_in,
                              void* d_out, int out_size, void* d_ws, size_t ws_size,
                              hipStream_t stream) {
  const float* x      = (const float*)d_in[0];
  const void*  mask   = d_in[1];
  const float* w_qkv  = (const float*)d_in[2];
  const float* w_proj = (const float*)d_in[3];
  const float* b_proj = (const float*)d_in[4];
  float* outp = (float*)d_out;
  char* ws = (char*)d_ws;

  int*      flag   = (int*)(ws + 0);
  unsigned* mbits  = (unsigned*)(ws + 1024);                 // 524288 B
  short*    xb     = (short*)(ws + 525312);                  // 25165824 B
  short*    wqkvT  = (short*)(ws + 25691136);                // 3538944 B
  short*    wprojT = (short*)(ws + 29230080);                // 1179648 B
  short*    qkvb   = (short*)(ws + 30409728);                // 37748736 B
  short*    attnb  = (short*)(ws + 68158464);                // 12582912 B

  detect_mask<<<1, 256, 0, stream>>>((const unsigned char*)mask, flag);
  pack_mask<<<512, 256, 0, stream>>>(mask, flag, mbits);
  conv_bf16<<<(MTOT * CDIM) / 2048, 256, 0, stream>>>(x, xb, MTOT * CDIM);
  transpose_conv<<<dim3(NQKV / 64, CDIM / 64), 256, 0, stream>>>(w_qkv, wqkvT, CDIM, NQKV);
  transpose_conv<<<dim3(CDIM / 64, CDIM / 64), 256, 0, stream>>>(w_proj, wprojT, CDIM, CDIM);
  gemm_bt<false><<<dim3(NQKV / 128, MTOT / 128), 256, 0, stream>>>(xb, wqkvT, qkvb, nullptr,
                                                                   MTOT, NQKV, CDIM);
  flash_attn<<<dim3(NSEQ / 64, NBATCH * NHEAD), 256, 0, stream>>>(
      qkvb, (const unsigned long long*)mbits, attnb);
  gemm_bt<true><<<dim3(CDIM / 128, MTOT / 128), 256, 0, stream>>>(attnb, wprojT, outp, b_proj,
                                                                  MTOT, CDIM, CDIM);
}

// Round 5
// 313.633 us; speedup vs baseline: 1.2515x; 1.2515x over previous
//
#include <hip/hip_runtime.h>

#define NSEQ 2048
#define CDIM 768
#define NBATCH 4
#define NHEAD 12
#define HD 64
#define MTOT (NBATCH * NSEQ)   // 8192
#define NQKV (3 * CDIM)        // 2304

typedef float f32x4 __attribute__((ext_vector_type(4)));
typedef short bf16x8 __attribute__((ext_vector_type(8)));
typedef short short4v __attribute__((ext_vector_type(4)));

__device__ __forceinline__ short f2bf(float f) {
  union { float f; unsigned u; } x; x.f = f;
  unsigned r = x.u + 0x7fffu + ((x.u >> 16) & 1u);   // RNE
  return (short)(r >> 16);
}

// async global->LDS, 16B per lane; LDS dest is wave-uniform base + lane*16
__device__ __forceinline__ void gload16(const short* g, short* l) {
  __builtin_amdgcn_global_load_lds((const __attribute__((address_space(1))) void*)g,
                                   (__attribute__((address_space(3))) void*)l, 16, 0, 0);
}

// swizzled LDS fragment read: tile rows = 64 shorts (128B), byte ^= (row&7)<<4
__device__ __forceinline__ const bf16x8* frag(const short* t, int row, int col) {
  int byt = (row << 7) + (col << 1);
  byt ^= (row & 7) << 4;
  return (const bf16x8*)((const char*)t + byt);
}

// ---------------- mask dtype detection (bool may arrive as u8 / i32 / f32) ----
__global__ __launch_bounds__(256) void detect_mask(const unsigned char* __restrict__ m,
                                                   int* __restrict__ flag) {
  __shared__ int f1, f23;
  if (threadIdx.x == 0) { f1 = 0; f23 = 0; }
  __syncthreads();
  int a = 0, b = 0;
  for (int i = threadIdx.x; i < 1024; i += 256) {
    if (m[i * 4 + 1]) a = 1;
    if (m[i * 4 + 2] | m[i * 4 + 3]) b = 1;
  }
  if (a) atomicOr(&f1, 1);
  if (b) atomicOr(&f23, 1);
  __syncthreads();
  if (threadIdx.x == 0) *flag = f1 ? 1 : (f23 ? 2 : 0);  // 1=u8, 2=f32, 0=i32
}

// ---------------- pack mask into bits: word w bit j = mask[w*32+j] -----------
__global__ __launch_bounds__(256) void pack_mask(const void* __restrict__ mask,
                                                 const int* __restrict__ flag,
                                                 unsigned* __restrict__ bits) {
  int wi = blockIdx.x * 256 + threadIdx.x;   // 0..131071
  int f = *flag;
  unsigned v = 0;
  if (f == 1) {
    const unsigned char* p = (const unsigned char*)mask + (size_t)wi * 32;
#pragma unroll
    for (int j = 0; j < 32; ++j) v |= (p[j] != 0 ? 1u : 0u) << j;
  } else if (f == 2) {
    const float* p = (const float*)mask + (size_t)wi * 32;
#pragma unroll
    for (int j = 0; j < 32; ++j) v |= (p[j] != 0.f ? 1u : 0u) << j;
  } else {
    const int* p = (const int*)mask + (size_t)wi * 32;
#pragma unroll
    for (int j = 0; j < 32; ++j) v |= (p[j] != 0 ? 1u : 0u) << j;
  }
  bits[wi] = v;
}

// ---------------- fp32 -> bf16 bulk convert (8 elems/thread) -----------------
__global__ __launch_bounds__(256) void conv_bf16(const float* __restrict__ in,
                                                 short* __restrict__ out, int n) {
  int i = (blockIdx.x * 256 + threadIdx.x) * 8;
  if (i >= n) return;
  f32x4 a = *(const f32x4*)&in[i];
  f32x4 b = *(const f32x4*)&in[i + 4];
  bf16x8 o;
#pragma unroll
  for (int j = 0; j < 4; ++j) o[j] = f2bf(a[j]);
#pragma unroll
  for (int j = 0; j < 4; ++j) o[4 + j] = f2bf(b[j]);
  *(bf16x8*)&out[i] = o;
}

// ---------------- transpose + convert: in fp32 [R][Cc] -> out bf16 [Cc][R] ---
__global__ __launch_bounds__(256) void transpose_conv(const float* __restrict__ in,
                                                      short* __restrict__ outp,
                                                      int R, int Cc) {
  __shared__ short tile[64][65];
  int c0 = blockIdx.x * 64, r0 = blockIdx.y * 64;
  int t = threadIdx.x;
  int tr = t >> 4;           // 0..15
  int tc = (t & 15) * 4;     // 0..60
  for (int rr = tr; rr < 64; rr += 16) {
    f32x4 v = *(const f32x4*)&in[(size_t)(r0 + rr) * Cc + c0 + tc];
#pragma unroll
    for (int j = 0; j < 4; ++j) tile[tc + j][rr] = f2bf(v[j]);
  }
  __syncthreads();
  for (int cc = tr; cc < 64; cc += 16) {
#pragma unroll
    for (int j = 0; j < 4; ++j)
      outp[(size_t)(c0 + cc) * R + r0 + tc + j] = tile[cc][tc + j];
  }
}

// ---------------- V transpose: qkv v-part [b][n][h][d] -> vt[b*h][d][n] ------
__global__ __launch_bounds__(256) void vtrans(const short* __restrict__ qkvb,
                                              short* __restrict__ vt) {
  __shared__ short t[64][72];
  int n0 = blockIdx.x * 64, bh = blockIdx.y;
  int b = bh / NHEAD, h = bh % NHEAD;
  int tid = threadIdx.x, r = tid >> 2, c0 = (tid & 3) * 16;
  const short* src = qkvb + (size_t)(b * NSEQ + n0 + r) * NQKV + 2 * CDIM + h * HD + c0;
  bf16x8 v0 = *(const bf16x8*)src;
  bf16x8 v1 = *(const bf16x8*)(src + 8);
  *(bf16x8*)&t[r][c0] = v0;
  *(bf16x8*)&t[r][c0 + 8] = v1;
  __syncthreads();
  bf16x8 o0, o1;
#pragma unroll
  for (int j = 0; j < 8; ++j) { o0[j] = t[c0 + j][r]; o1[j] = t[c0 + 8 + j][r]; }
  short* dst = vt + (size_t)(bh * HD + r) * NSEQ + n0 + c0;
  *(bf16x8*)&dst[0] = o0;
  *(bf16x8*)&dst[8] = o1;
}

// ---------------- bf16 GEMM: C[M,N] = A[M,K] * Bt[N,K]^T (+bias, f32 out) ----
// 128x128 tile, BK=32, 4 waves of 64x64; global_load_lds width-16 staging
template <bool F32OUT>
__global__ __launch_bounds__(256) void gemm_bt(const short* __restrict__ A,
                                               const short* __restrict__ Bt,
                                               void* __restrict__ Cout,
                                               const float* __restrict__ bias,
                                               int Mdim, int Ndim, int Kdim) {
  __shared__ short As[128 * 32];
  __shared__ short Bs[128 * 32];
  const int tid = threadIdx.x;
  const int lane = tid & 63;
  const int w = tid >> 6;
  const int wm = (w >> 1) * 64, wn = (w & 1) * 64;
  const int lr = lane & 15, lh = lane >> 4;
  const int m0 = blockIdx.y * 128, n0 = blockIdx.x * 128;

  f32x4 acc[4][4];
#pragma unroll
  for (int i = 0; i < 4; ++i)
#pragma unroll
    for (int j = 0; j < 4; ++j) acc[i][j] = (f32x4){0.f, 0.f, 0.f, 0.f};

  // staging: wave w covers rows w*32..w*32+31 (2 instr), lane l -> row +(l>>2), chunk l&3
  const int srow = w * 32 + (lane >> 2);
  const int scol = (lane & 3) * 8;
  const short* Ap = A + (size_t)(m0 + srow) * Kdim + scol;
  const short* Bp = Bt + (size_t)(n0 + srow) * Kdim + scol;
  short* AsW0 = &As[(w * 32) * 32];
  short* AsW1 = &As[(w * 32 + 16) * 32];
  short* BsW0 = &Bs[(w * 32) * 32];
  short* BsW1 = &Bs[(w * 32 + 16) * 32];

  for (int k0 = 0; k0 < Kdim; k0 += 32) {
    __syncthreads();
    gload16(Ap + k0, AsW0);
    gload16(Ap + (size_t)16 * Kdim + k0, AsW1);
    gload16(Bp + k0, BsW0);
    gload16(Bp + (size_t)16 * Kdim + k0, BsW1);
    __syncthreads();
    bf16x8 a[4], b[4];
#pragma unroll
    for (int i = 0; i < 4; ++i) a[i] = *(const bf16x8*)&As[(wm + i * 16 + lr) * 32 + lh * 8];
#pragma unroll
    for (int j = 0; j < 4; ++j) b[j] = *(const bf16x8*)&Bs[(wn + j * 16 + lr) * 32 + lh * 8];
#pragma unroll
    for (int i = 0; i < 4; ++i)
#pragma unroll
      for (int j = 0; j < 4; ++j)
        acc[i][j] = __builtin_amdgcn_mfma_f32_16x16x32_bf16(a[i], b[j], acc[i][j], 0, 0, 0);
  }

#pragma unroll
  for (int i = 0; i < 4; ++i) {
    int mrowb = m0 + wm + i * 16 + lh * 4;
#pragma unroll
    for (int j = 0; j < 4; ++j) {
      int ncol = n0 + wn + j * 16 + lr;
#pragma unroll
      for (int r = 0; r < 4; ++r) {
        float v = acc[i][j][r];
        if (F32OUT)
          ((float*)Cout)[(size_t)(mrowb + r) * Ndim + ncol] = v + bias[ncol];
        else
          ((short*)Cout)[(size_t)(mrowb + r) * Ndim + ncol] = f2bf(v);
      }
    }
  }
}

// ---------------- flash attention, swapped QK^T (S^T = K·Q^T) ----------------
// 4 waves x 16 q-rows, KVBLK=64; lane (lr,lh) owns q=lr, kv-subset nb*16+lh*4+r
__global__ __launch_bounds__(256) void flash_attn(const short* __restrict__ qkv,
                                                  const short* __restrict__ vtb,
                                                  const unsigned long long* __restrict__ mbits,
                                                  short* __restrict__ outp) {
  __shared__ short Qs[64 * 64];
  __shared__ short Ks[64 * 64];
  __shared__ short Vt[64 * 64];

  const int tid = threadIdx.x;
  const int lane = tid & 63;
  const int w = tid >> 6;
  const int lr = lane & 15, lh = lane >> 4;
  const int q0 = blockIdx.x * 64;
  const int bh = blockIdx.y;
  const int b = bh / NHEAD, h = bh % NHEAD;

  // gload geometry: per instr 8 rows x 128B; pre-swizzled source chunk
  const int srow = lane >> 3;                 // 0..7
  const int schunk = (lane & 7) ^ srow;       // inverse of read-side XOR swizzle

  {
    const short* qb = qkv + (size_t)(b * NSEQ + q0 + w * 16 + srow) * NQKV + h * HD + schunk * 8;
    gload16(qb, &Qs[(w * 16) * 64]);
    gload16(qb + (size_t)8 * NQKV, &Qs[(w * 16 + 8) * 64]);
  }
  __syncthreads();
  const bf16x8 qf0 = *frag(Qs, w * 16 + lr, lh * 8);
  const bf16x8 qf1 = *frag(Qs, w * 16 + lr, 32 + lh * 8);

  float m_r = -1e30f, l_r = 0.f;
  f32x4 o[4];
#pragma unroll
  for (int nd = 0; nd < 4; ++nd) o[nd] = (f32x4){0.f, 0.f, 0.f, 0.f};

  const short* kbase = qkv + (size_t)(b * NSEQ) * NQKV + CDIM + h * HD;
  const short* vbase = vtb + (size_t)(bh * HD) * NSEQ;
  const int srcA = (lh & 1) * 32 + lr;   // lane holding kv bits [8*(lh&1) .. +3]
  const int srcB = srcA + 16;            // lane holding kv bits [8*(lh&1)+4 .. +7]
  const int nbh = lh >> 1;               // which nb-half this lane consumes

  for (int kv0 = 0; kv0 < NSEQ; kv0 += 64) {
    unsigned long long mw = mbits[(size_t)(q0 + w * 16 + lr) * (NSEQ / 64) + (kv0 >> 6)];
    __syncthreads();
    {
      const short* kb = kbase + (size_t)(kv0 + w * 16 + srow) * NQKV + schunk * 8;
      gload16(kb, &Ks[(w * 16) * 64]);
      gload16(kb + (size_t)8 * NQKV, &Ks[(w * 16 + 8) * 64]);
      const short* vb = vbase + (size_t)(w * 16 + srow) * NSEQ + kv0 + schunk * 8;
      gload16(vb, &Vt[(w * 16) * 64]);
      gload16(vb + (size_t)8 * NSEQ, &Vt[(w * 16 + 8) * 64]);
    }
    __syncthreads();

    // S^T tiles: p[nb][r] = S[q0+w*16+lr][kv0 + nb*16 + lh*4 + r]
    float p[4][4];
#pragma unroll
    for (int nb = 0; nb < 4; ++nb) {
      f32x4 st = (f32x4){0.f, 0.f, 0.f, 0.f};
      st = __builtin_amdgcn_mfma_f32_16x16x32_bf16(*frag(Ks, nb * 16 + lr, lh * 8), qf0, st, 0, 0, 0);
      st = __builtin_amdgcn_mfma_f32_16x16x32_bf16(*frag(Ks, nb * 16 + lr, 32 + lh * 8), qf1, st, 0, 0, 0);
      unsigned m4 = ((unsigned)(mw >> (nb * 16 + lh * 4))) & 15u;
#pragma unroll
      for (int r = 0; r < 4; ++r)
        p[nb][r] = ((m4 >> r) & 1u) ? -3e38f : st[r] * 0.125f;
    }

    // online softmax: one q-row per lane, spread over 4 lanes (lh)
    float pm = p[0][0];
#pragma unroll
    for (int nb = 0; nb < 4; ++nb)
#pragma unroll
      for (int r = 0; r < 4; ++r) pm = fmaxf(pm, p[nb][r]);
    pm = fmaxf(pm, __shfl_xor(pm, 16, 64));
    pm = fmaxf(pm, __shfl_xor(pm, 32, 64));
    float nm = fmaxf(m_r, pm);
    float al = __expf(m_r - nm);
    m_r = nm;
    float rs = 0.f;
#pragma unroll
    for (int nb = 0; nb < 4; ++nb)
#pragma unroll
      for (int r = 0; r < 4; ++r) {
        float e = __expf(p[nb][r] - nm);
        p[nb][r] = e;
        rs += e;
      }
    rs += __shfl_xor(rs, 16, 64);
    rs += __shfl_xor(rs, 32, 64);
    l_r = l_r * al + rs;
#pragma unroll
    for (int nd = 0; nd < 4; ++nd)
#pragma unroll
      for (int r = 0; r < 4; ++r) o[nd][r] *= al;

    // pack P to bf16 pairs, exchange across lh-groups to build PV B-fragments
    unsigned pk[4][2];
#pragma unroll
    for (int nb = 0; nb < 4; ++nb) {
      asm("v_cvt_pk_bf16_f32 %0, %1, %2" : "=v"(pk[nb][0]) : "v"(p[nb][0]), "v"(p[nb][1]));
      asm("v_cvt_pk_bf16_f32 %0, %1, %2" : "=v"(pk[nb][1]) : "v"(p[nb][2]), "v"(p[nb][3]));
    }
    bf16x8 pb[2];
#pragma unroll
    for (int c = 0; c < 2; ++c) {
      unsigned a0 = __shfl(pk[2 * c][0], srcA, 64);
      unsigned a1 = __shfl(pk[2 * c][1], srcA, 64);
      unsigned a2 = __shfl(pk[2 * c][0], srcB, 64);
      unsigned a3 = __shfl(pk[2 * c][1], srcB, 64);
      unsigned b0 = __shfl(pk[2 * c + 1][0], srcA, 64);
      unsigned b1 = __shfl(pk[2 * c + 1][1], srcA, 64);
      unsigned b2 = __shfl(pk[2 * c + 1][0], srcB, 64);
      unsigned b3 = __shfl(pk[2 * c + 1][1], srcB, 64);
      union { unsigned u[4]; bf16x8 v; } uu;
      uu.u[0] = nbh ? b0 : a0;
      uu.u[1] = nbh ? b1 : a1;
      uu.u[2] = nbh ? b2 : a2;
      uu.u[3] = nbh ? b3 : a3;
      pb[c] = uu.v;
    }

    // O^T += V^T · P^T
#pragma unroll
    for (int nd = 0; nd < 4; ++nd) {
      o[nd] = __builtin_amdgcn_mfma_f32_16x16x32_bf16(*frag(Vt, nd * 16 + lr, lh * 8), pb[0], o[nd], 0, 0, 0);
      o[nd] = __builtin_amdgcn_mfma_f32_16x16x32_bf16(*frag(Vt, nd * 16 + lr, 32 + lh * 8), pb[1], o[nd], 0, 0, 0);
    }
  }

  const float inv = 1.f / l_r;
  short* orow = outp + (size_t)(b * NSEQ + q0 + w * 16 + lr) * CDIM + h * HD + lh * 4;
#pragma unroll
  for (int nd = 0; nd < 4; ++nd) {
    short4v sv;
#pragma unroll
    for (int r = 0; r < 4; ++r) sv[r] = f2bf(o[nd][r] * inv);
    *(short4v*)&orow[nd * 16] = sv;
  }
}

// ---------------- launch --------------------------------------------------
extern "C" void kernel_launch(void* const* d_in, const int* in_sizes, int n_in,
                              void* d_out, int out_size, void* d_ws, size_t ws_size,
                              hipStream_t stream) {
  const float* x      = (const float*)d_in[0];
  const void*  mask   = d_in[1];
  const float* w_qkv  = (const float*)d_in[2];
  const float* w_proj = (const float*)d_in[3];
  const float* b_proj = (const float*)d_in[4];
  float* outp = (float*)d_out;
  char* ws = (char*)d_ws;

  int*      flag   = (int*)(ws + 0);
  unsigned* mbits  = (unsigned*)(ws + 1024);                 // 524288 B
  short*    xb     = (short*)(ws + 525312);                  // 25165824 B (freed after QKV GEMM)
  short*    wqkvT  = (short*)(ws + 25691136);                // 3538944 B
  short*    wprojT = (short*)(ws + 29230080);                // 1179648 B
  short*    qkvb   = (short*)(ws + 30409728);                // 37748736 B
  short*    attnb  = (short*)(ws + 68158464);                // 12582912 B
  short*    vtb    = xb;                                     // reuse xb: 12582912 B needed

  detect_mask<<<1, 256, 0, stream>>>((const unsigned char*)mask, flag);
  pack_mask<<<512, 256, 0, stream>>>(mask, flag, mbits);
  conv_bf16<<<(MTOT * CDIM) / 2048, 256, 0, stream>>>(x, xb, MTOT * CDIM);
  transpose_conv<<<dim3(NQKV / 64, CDIM / 64), 256, 0, stream>>>(w_qkv, wqkvT, CDIM, NQKV);
  transpose_conv<<<dim3(CDIM / 64, CDIM / 64), 256, 0, stream>>>(w_proj, wprojT, CDIM, CDIM);
  gemm_bt<false><<<dim3(NQKV / 128, MTOT / 128), 256, 0, stream>>>(xb, wqkvT, qkvb, nullptr,
                                                                   MTOT, NQKV, CDIM);
  vtrans<<<dim3(NSEQ / 64, NBATCH * NHEAD), 256, 0, stream>>>(qkvb, vtb);
  flash_attn<<<dim3(NSEQ / 64, NBATCH * NHEAD), 256, 0, stream>>>(
      qkvb, vtb, (const unsigned long long*)mbits, attnb);
  gemm_bt<true><<<dim3(CDIM / 128, MTOT / 128), 256, 0, stream>>>(attnb, wprojT, outp, b_proj,
                                                                  MTOT, CDIM, CDIM);
}

// Round 8
// 308.907 us; speedup vs baseline: 1.2707x; 1.0153x over previous
//
#include <hip/hip_runtime.h>

#define NSEQ 2048
#define CDIM 768
#define NBATCH 4
#define NHEAD 12
#define HD 64
#define MTOT (NBATCH * NSEQ)   // 8192
#define NQKV (3 * CDIM)        // 2304

typedef float f32x4 __attribute__((ext_vector_type(4)));
typedef short bf16x8 __attribute__((ext_vector_type(8)));
typedef short short4v __attribute__((ext_vector_type(4)));

__device__ __forceinline__ short f2bf(float f) {
  union { float f; unsigned u; } x; x.f = f;
  unsigned r = x.u + 0x7fffu + ((x.u >> 16) & 1u);   // RNE
  return (short)(r >> 16);
}

__device__ __forceinline__ float exp2a(float x) {   // v_exp_f32: 2^x
  float r; asm("v_exp_f32 %0, %1" : "=v"(r) : "v"(x)); return r;
}

// async global->LDS, 16B per lane; LDS dest is wave-uniform base + lane*16
__device__ __forceinline__ void gload16(const short* g, short* l) {
  __builtin_amdgcn_global_load_lds((const __attribute__((address_space(1))) void*)g,
                                   (__attribute__((address_space(3))) void*)l, 16, 0, 0);
}

// swizzled LDS fragment read: tile rows = 64 shorts (128B), byte ^= (row&7)<<4
__device__ __forceinline__ const bf16x8* frag(const short* t, int row, int col) {
  int byt = (row << 7) + (col << 1);
  byt ^= (row & 7) << 4;
  return (const bf16x8*)((const char*)t + byt);
}

// ---------------- mask dtype detection (bool may arrive as u8 / i32 / f32) ----
__global__ __launch_bounds__(256) void detect_mask(const unsigned char* __restrict__ m,
                                                   int* __restrict__ flag) {
  __shared__ int f1, f23;
  if (threadIdx.x == 0) { f1 = 0; f23 = 0; }
  __syncthreads();
  int a = 0, b = 0;
  for (int i = threadIdx.x; i < 1024; i += 256) {
    if (m[i * 4 + 1]) a = 1;
    if (m[i * 4 + 2] | m[i * 4 + 3]) b = 1;
  }
  if (a) atomicOr(&f1, 1);
  if (b) atomicOr(&f23, 1);
  __syncthreads();
  if (threadIdx.x == 0) *flag = f1 ? 1 : (f23 ? 2 : 0);  // 1=u8, 2=f32, 0=i32
}

// ---------------- pack mask into bits: word w bit j = mask[w*32+j] -----------
__global__ __launch_bounds__(256) void pack_mask(const void* __restrict__ mask,
                                                 const int* __restrict__ flag,
                                                 unsigned* __restrict__ bits) {
  int wi = blockIdx.x * 256 + threadIdx.x;   // 0..131071
  int f = *flag;
  unsigned v = 0;
  if (f == 1) {
    const unsigned char* p = (const unsigned char*)mask + (size_t)wi * 32;
#pragma unroll
    for (int j = 0; j < 32; ++j) v |= (p[j] != 0 ? 1u : 0u) << j;
  } else if (f == 2) {
    const float* p = (const float*)mask + (size_t)wi * 32;
#pragma unroll
    for (int j = 0; j < 32; ++j) v |= (p[j] != 0.f ? 1u : 0u) << j;
  } else {
    const int* p = (const int*)mask + (size_t)wi * 32;
#pragma unroll
    for (int j = 0; j < 32; ++j) v |= (p[j] != 0 ? 1u : 0u) << j;
  }
  bits[wi] = v;
}

// ---------------- fp32 -> bf16 bulk convert (8 elems/thread) -----------------
__global__ __launch_bounds__(256) void conv_bf16(const float* __restrict__ in,
                                                 short* __restrict__ out, int n) {
  int i = (blockIdx.x * 256 + threadIdx.x) * 8;
  if (i >= n) return;
  f32x4 a = *(const f32x4*)&in[i];
  f32x4 b = *(const f32x4*)&in[i + 4];
  bf16x8 o;
#pragma unroll
  for (int j = 0; j < 4; ++j) o[j] = f2bf(a[j]);
#pragma unroll
  for (int j = 0; j < 4; ++j) o[4 + j] = f2bf(b[j]);
  *(bf16x8*)&out[i] = o;
}

// ---------------- transpose + convert: in fp32 [R][Cc] -> out bf16 [Cc][R] ---
__global__ __launch_bounds__(256) void transpose_conv(const float* __restrict__ in,
                                                      short* __restrict__ outp,
                                                      int R, int Cc) {
  __shared__ short tile[64][65];
  int c0 = blockIdx.x * 64, r0 = blockIdx.y * 64;
  int t = threadIdx.x;
  int tr = t >> 4;           // 0..15
  int tc = (t & 15) * 4;     // 0..60
  for (int rr = tr; rr < 64; rr += 16) {
    f32x4 v = *(const f32x4*)&in[(size_t)(r0 + rr) * Cc + c0 + tc];
#pragma unroll
    for (int j = 0; j < 4; ++j) tile[tc + j][rr] = f2bf(v[j]);
  }
  __syncthreads();
  for (int cc = tr; cc < 64; cc += 16) {
#pragma unroll
    for (int j = 0; j < 4; ++j)
      outp[(size_t)(c0 + cc) * R + r0 + tc + j] = tile[cc][tc + j];
  }
}

// ---------------- V transpose: qkv v-part [b][n][h][d] -> vt[b*h][d][n] ------
__global__ __launch_bounds__(256) void vtrans(const short* __restrict__ qkvb,
                                              short* __restrict__ vt) {
  __shared__ short t[64][72];
  int n0 = blockIdx.x * 64, bh = blockIdx.y;
  int b = bh / NHEAD, h = bh % NHEAD;
  int tid = threadIdx.x, r = tid >> 2, c0 = (tid & 3) * 16;
  const short* src = qkvb + (size_t)(b * NSEQ + n0 + r) * NQKV + 2 * CDIM + h * HD + c0;
  bf16x8 v0 = *(const bf16x8*)src;
  bf16x8 v1 = *(const bf16x8*)(src + 8);
  *(bf16x8*)&t[r][c0] = v0;
  *(bf16x8*)&t[r][c0 + 8] = v1;
  __syncthreads();
  bf16x8 o0, o1;
#pragma unroll
  for (int j = 0; j < 8; ++j) { o0[j] = t[c0 + j][r]; o1[j] = t[c0 + 8 + j][r]; }
  short* dst = vt + (size_t)(bh * HD + r) * NSEQ + n0 + c0;
  *(bf16x8*)&dst[0] = o0;
  *(bf16x8*)&dst[8] = o1;
}

// ---------------- bf16 GEMM: C[M,N] = A[M,K] * Bt[N,K]^T (+bias, f32 out) ----
// 128x128 tile, BK=32, 4 waves of 64x64; double-buffered LDS, counted vmcnt
template <bool F32OUT>
__global__ __launch_bounds__(256) void gemm_bt(const short* __restrict__ A,
                                               const short* __restrict__ Bt,
                                               void* __restrict__ Cout,
                                               const float* __restrict__ bias,
                                               int Mdim, int Ndim, int Kdim) {
  __shared__ short As[2][128 * 32];
  __shared__ short Bs[2][128 * 32];
  const int tid = threadIdx.x;
  const int lane = tid & 63;
  const int w = tid >> 6;
  const int wm = (w >> 1) * 64, wn = (w & 1) * 64;
  const int lr = lane & 15, lh = lane >> 4;
  const int m0 = blockIdx.y * 128, n0 = blockIdx.x * 128;

  f32x4 acc[4][4];
#pragma unroll
  for (int i = 0; i < 4; ++i)
#pragma unroll
    for (int j = 0; j < 4; ++j) acc[i][j] = (f32x4){0.f, 0.f, 0.f, 0.f};

  // staging: wave w covers rows w*32..w*32+31 (2 instr each for A,B)
  const int srow = w * 32 + (lane >> 2);
  const int scol = (lane & 3) * 8;
  const short* Ap = A + (size_t)(m0 + srow) * Kdim + scol;
  const short* Bp = Bt + (size_t)(n0 + srow) * Kdim + scol;
  const int l0 = (w * 32) * 32;
  const int l1 = (w * 32 + 16) * 32;

  auto tilecompute = [&](const short* Asb, const short* Bsb) {
    bf16x8 a[4], b[4];
#pragma unroll
    for (int i = 0; i < 4; ++i) a[i] = *(const bf16x8*)&Asb[(wm + i * 16 + lr) * 32 + lh * 8];
#pragma unroll
    for (int j = 0; j < 4; ++j) b[j] = *(const bf16x8*)&Bsb[(wn + j * 16 + lr) * 32 + lh * 8];
#pragma unroll
    for (int i = 0; i < 4; ++i)
#pragma unroll
      for (int j = 0; j < 4; ++j)
        acc[i][j] = __builtin_amdgcn_mfma_f32_16x16x32_bf16(a[i], b[j], acc[i][j], 0, 0, 0);
  };

  // prologue: stage tile 0 into buffer 0
  gload16(Ap, &As[0][l0]);
  gload16(Ap + (size_t)16 * Kdim, &As[0][l1]);
  gload16(Bp, &Bs[0][l0]);
  gload16(Bp + (size_t)16 * Kdim, &Bs[0][l1]);

  const int NT = Kdim >> 5;
  for (int t = 0; t < NT - 1; ++t) {
    const int cur = t & 1, nxt = cur ^ 1;
    const int k1 = (t + 1) << 5;
    gload16(Ap + k1, &As[nxt][l0]);
    gload16(Ap + (size_t)16 * Kdim + k1, &As[nxt][l1]);
    gload16(Bp + k1, &Bs[nxt][l0]);
    gload16(Bp + (size_t)16 * Kdim + k1, &Bs[nxt][l1]);
    asm volatile("s_waitcnt vmcnt(4)" ::: "memory");   // tile t landed; t+1 in flight
    __builtin_amdgcn_s_barrier();
    tilecompute(As[cur], Bs[cur]);
    __builtin_amdgcn_s_barrier();
  }
  asm volatile("s_waitcnt vmcnt(0)" ::: "memory");
  __builtin_amdgcn_s_barrier();
  tilecompute(As[(NT - 1) & 1], Bs[(NT - 1) & 1]);

#pragma unroll
  for (int i = 0; i < 4; ++i) {
    int mrowb = m0 + wm + i * 16 + lh * 4;
#pragma unroll
    for (int j = 0; j < 4; ++j) {
      int ncol = n0 + wn + j * 16 + lr;
#pragma unroll
      for (int r = 0; r < 4; ++r) {
        float v = acc[i][j][r];
        if (F32OUT)
          ((float*)Cout)[(size_t)(mrowb + r) * Ndim + ncol] = v + bias[ncol];
        else
          ((short*)Cout)[(size_t)(mrowb + r) * Ndim + ncol] = f2bf(v);
      }
    }
  }
}

// ---------------- flash attention, swapped QK^T (S^T = K·Q^T) ----------------
// 4 waves x 16 q-rows, KVBLK=64; K/V double-buffered, counted vmcnt,
// exp2-domain softmax + defer-max. Q in registers.
__global__ __launch_bounds__(256) void flash_attn(const short* __restrict__ qkv,
                                                  const short* __restrict__ vtb,
                                                  const unsigned long long* __restrict__ mbits,
                                                  short* __restrict__ outp) {
  __shared__ short KB[2][64 * 64];
  __shared__ short VB[2][64 * 64];

  const int tid = threadIdx.x;
  const int lane = tid & 63;
  const int w = tid >> 6;
  const int lr = lane & 15, lh = lane >> 4;
  const int q0 = blockIdx.x * 64;
  const int bh = blockIdx.y;
  const int b = bh / NHEAD, h = bh % NHEAD;

  // gload geometry: per instr 8 rows x 128B; pre-swizzled source chunk
  const int srow = lane >> 3;                 // 0..7
  const int schunk = (lane & 7) ^ srow;       // inverse of read-side XOR swizzle

  // Q fragments straight to registers (each lane reads only its own q-row)
  const short* qrow = qkv + (size_t)(b * NSEQ + q0 + w * 16 + lr) * NQKV + h * HD;
  const bf16x8 qf0 = *(const bf16x8*)(qrow + lh * 8);
  const bf16x8 qf1 = *(const bf16x8*)(qrow + 32 + lh * 8);
  asm volatile("" ::: "memory");   // pin q loads before the gload stream

  const short* kbase = qkv + (size_t)(b * NSEQ + w * 16 + srow) * NQKV + CDIM + h * HD + schunk * 8;
  const short* vbase = vtb + (size_t)(bh * HD + w * 16 + srow) * NSEQ + schunk * 8;

  // stage tile 0
  gload16(kbase, &KB[0][(w * 16) * 64]);
  gload16(kbase + (size_t)8 * NQKV, &KB[0][(w * 16 + 8) * 64]);
  gload16(vbase, &VB[0][(w * 16) * 64]);
  gload16(vbase + (size_t)8 * NSEQ, &VB[0][(w * 16 + 8) * 64]);

  const unsigned long long* mrow = mbits + (size_t)(q0 + w * 16 + lr) * (NSEQ / 64);
  unsigned long long mw = mrow[0];

  float m_r = -1e30f, l_r = 0.f;
  f32x4 o[4];
#pragma unroll
  for (int nd = 0; nd < 4; ++nd) o[nd] = (f32x4){0.f, 0.f, 0.f, 0.f};

  const int srcA = (lh & 1) * 32 + lr;   // lane holding kv bits [8*(lh&1) .. +3]
  const int srcB = srcA + 16;            // lane holding kv bits [8*(lh&1)+4 .. +7]
  const int nbh = lh >> 1;               // which nb-half this lane consumes
  const float C2 = 0.18033688f;          // 0.125 * log2(e)

  auto compute = [&](const short* Kb, const short* Vb, unsigned long long mwv) {
    // S^T tiles: p[nb][r] = S[q=lr][kv = nb*16 + lh*4 + r] (exp2-domain scale)
    float p[4][4];
#pragma unroll
    for (int nb = 0; nb < 4; ++nb) {
      f32x4 st = (f32x4){0.f, 0.f, 0.f, 0.f};
      st = __builtin_amdgcn_mfma_f32_16x16x32_bf16(*frag(Kb, nb * 16 + lr, lh * 8), qf0, st, 0, 0, 0);
      st = __builtin_amdgcn_mfma_f32_16x16x32_bf16(*frag(Kb, nb * 16 + lr, 32 + lh * 8), qf1, st, 0, 0, 0);
      unsigned m4 = ((unsigned)(mwv >> (nb * 16 + lh * 4))) & 15u;
#pragma unroll
      for (int r = 0; r < 4; ++r)
        p[nb][r] = ((m4 >> r) & 1u) ? -3e38f : st[r] * C2;
    }

    // online softmax (row lives in 4 lanes: lr fixed, lh varies)
    float pm = p[0][0];
#pragma unroll
    for (int nb = 0; nb < 4; ++nb)
#pragma unroll
      for (int r = 0; r < 4; ++r) pm = fmaxf(pm, p[nb][r]);
    pm = fmaxf(pm, __shfl_xor(pm, 16, 64));
    pm = fmaxf(pm, __shfl_xor(pm, 32, 64));

    if (__any(pm > m_r + 8.f)) {        // defer-max: rescale only on real growth
      float nm = fmaxf(m_r, pm);
      float al = exp2a(m_r - nm);
      m_r = nm;
      l_r *= al;
#pragma unroll
      for (int nd = 0; nd < 4; ++nd)
#pragma unroll
        for (int r = 0; r < 4; ++r) o[nd][r] *= al;
    }
    float rs = 0.f;
#pragma unroll
    for (int nb = 0; nb < 4; ++nb)
#pragma unroll
      for (int r = 0; r < 4; ++r) {
        float e = exp2a(p[nb][r] - m_r);
        p[nb][r] = e;
        rs += e;
      }
    rs += __shfl_xor(rs, 16, 64);
    rs += __shfl_xor(rs, 32, 64);
    l_r += rs;

    // pack P to bf16 pairs, exchange across lh-groups to build PV B-fragments
    unsigned pk[4][2];
#pragma unroll
    for (int nb = 0; nb < 4; ++nb) {
      asm("v_cvt_pk_bf16_f32 %0, %1, %2" : "=v"(pk[nb][0]) : "v"(p[nb][0]), "v"(p[nb][1]));
      asm("v_cvt_pk_bf16_f32 %0, %1, %2" : "=v"(pk[nb][1]) : "v"(p[nb][2]), "v"(p[nb][3]));
    }
    bf16x8 pb[2];
#pragma unroll
    for (int c = 0; c < 2; ++c) {
      unsigned a0 = __shfl(pk[2 * c][0], srcA, 64);
      unsigned a1 = __shfl(pk[2 * c][1], srcA, 64);
      unsigned a2 = __shfl(pk[2 * c][0], srcB, 64);
      unsigned a3 = __shfl(pk[2 * c][1], srcB, 64);
      unsigned b0 = __shfl(pk[2 * c + 1][0], srcA, 64);
      unsigned b1 = __shfl(pk[2 * c + 1][1], srcA, 64);
      unsigned b2 = __shfl(pk[2 * c + 1][0], srcB, 64);
      unsigned b3 = __shfl(pk[2 * c + 1][1], srcB, 64);
      union { unsigned u[4]; bf16x8 v; } uu;
      uu.u[0] = nbh ? b0 : a0;
      uu.u[1] = nbh ? b1 : a1;
      uu.u[2] = nbh ? b2 : a2;
      uu.u[3] = nbh ? b3 : a3;
      pb[c] = uu.v;
    }

    // O^T += V^T · P^T
#pragma unroll
    for (int nd = 0; nd < 4; ++nd) {
      o[nd] = __builtin_amdgcn_mfma_f32_16x16x32_bf16(*frag(Vb, nd * 16 + lr, lh * 8), pb[0], o[nd], 0, 0, 0);
      o[nd] = __builtin_amdgcn_mfma_f32_16x16x32_bf16(*frag(Vb, nd * 16 + lr, 32 + lh * 8), pb[1], o[nd], 0, 0, 0);
    }
  };

  for (int t = 0; t < 31; ++t) {
    const int cur = t & 1, nxt = cur ^ 1;
    {
      const short* kb = kbase + (size_t)(t + 1) * 64 * NQKV;
      gload16(kb, &KB[nxt][(w * 16) * 64]);
      gload16(kb + (size_t)8 * NQKV, &KB[nxt][(w * 16 + 8) * 64]);
      const short* vb = vbase + (t + 1) * 64;
      gload16(vb, &VB[nxt][(w * 16) * 64]);
      gload16(vb + (size_t)8 * NSEQ, &VB[nxt][(w * 16 + 8) * 64]);
    }
    asm volatile("s_waitcnt vmcnt(4)" ::: "memory");   // tile t (+mask t) landed
    unsigned long long mw_next = mrow[t + 1];
    __builtin_amdgcn_s_barrier();
    compute(KB[cur], VB[cur], mw);
    mw = mw_next;
    __builtin_amdgcn_s_barrier();
  }
  asm volatile("s_waitcnt vmcnt(0)" ::: "memory");
  __builtin_amdgcn_s_barrier();
  compute(KB[1], VB[1], mw);

  const float inv = 1.f / l_r;
  short* orow = outp + (size_t)(b * NSEQ + q0 + w * 16 + lr) * CDIM + h * HD + lh * 4;
#pragma unroll
  for (int nd = 0; nd < 4; ++nd) {
    short4v sv;
#pragma unroll
    for (int r = 0; r < 4; ++r) sv[r] = f2bf(o[nd][r] * inv);
    *(short4v*)&orow[nd * 16] = sv;
  }
}

// ---------------- launch --------------------------------------------------
extern "C" void kernel_launch(void* const* d_in, const int* in_sizes, int n_in,
                              void* d_out, int out_size, void* d_ws, size_t ws_size,
                              hipStream_t stream) {
  const float* x      = (const float*)d_in[0];
  const void*  mask   = d_in[1];
  const float* w_qkv  = (const float*)d_in[2];
  const float* w_proj = (const float*)d_in[3];
  const float* b_proj = (const float*)d_in[4];
  float* outp = (float*)d_out;
  char* ws = (char*)d_ws;

  int*      flag   = (int*)(ws + 0);
  unsigned* mbits  = (unsigned*)(ws + 1024);                 // 524288 B
  short*    xb     = (short*)(ws + 525312);                  // 25165824 B (freed after QKV GEMM)
  short*    wqkvT  = (short*)(ws + 25691136);                // 3538944 B
  short*    wprojT = (short*)(ws + 29230080);                // 1179648 B
  short*    qkvb   = (short*)(ws + 30409728);                // 37748736 B
  short*    attnb  = (short*)(ws + 68158464);                // 12582912 B
  short*    vtb    = xb;                                     // reuse xb: 12582912 B needed

  detect_mask<<<1, 256, 0, stream>>>((const unsigned char*)mask, flag);
  pack_mask<<<512, 256, 0, stream>>>(mask, flag, mbits);
  conv_bf16<<<(MTOT * CDIM) / 2048, 256, 0, stream>>>(x, xb, MTOT * CDIM);
  transpose_conv<<<dim3(NQKV / 64, CDIM / 64), 256, 0, stream>>>(w_qkv, wqkvT, CDIM, NQKV);
  transpose_conv<<<dim3(CDIM / 64, CDIM / 64), 256, 0, stream>>>(w_proj, wprojT, CDIM, CDIM);
  gemm_bt<false><<<dim3(NQKV / 128, MTOT / 128), 256, 0, stream>>>(xb, wqkvT, qkvb, nullptr,
                                                                   MTOT, NQKV, CDIM);
  vtrans<<<dim3(NSEQ / 64, NBATCH * NHEAD), 256, 0, stream>>>(qkvb, vtb);
  flash_attn<<<dim3(NSEQ / 64, NBATCH * NHEAD), 256, 0, stream>>>(
      qkvb, vtb, (const unsigned long long*)mbits, attnb);
  gemm_bt<true><<<dim3(CDIM / 128, MTOT / 128), 256, 0, stream>>>(attnb, wprojT, outp, b_proj,
                                                                  MTOT, CDIM, CDIM);
}

// Round 11
// 292.335 us; speedup vs baseline: 1.3427x; 1.0567x over previous
//
#include <hip/hip_runtime.h>

#define NSEQ 2048
#define CDIM 768
#define NBATCH 4
#define NHEAD 12
#define HD 64
#define MTOT (NBATCH * NSEQ)   // 8192
#define NQKV (3 * CDIM)        // 2304

typedef float f32x4 __attribute__((ext_vector_type(4)));
typedef float f32x16 __attribute__((ext_vector_type(16)));
typedef short bf16x8 __attribute__((ext_vector_type(8)));
typedef short short4v __attribute__((ext_vector_type(4)));

__device__ __forceinline__ short f2bf(float f) {
  union { float f; unsigned u; } x; x.f = f;
  unsigned r = x.u + 0x7fffu + ((x.u >> 16) & 1u);   // RNE
  return (short)(r >> 16);
}

__device__ __forceinline__ float exp2a(float x) {   // v_exp_f32: 2^x
  float r; asm("v_exp_f32 %0, %1" : "=v"(r) : "v"(x)); return r;
}

__device__ __forceinline__ unsigned cvtpk(float lo, float hi) {
  unsigned r; asm("v_cvt_pk_bf16_f32 %0, %1, %2" : "=v"(r) : "v"(lo), "v"(hi)); return r;
}

// async global->LDS, 16B per lane; LDS dest is wave-uniform base + lane*16
__device__ __forceinline__ void gload16(const short* g, short* l) {
  __builtin_amdgcn_global_load_lds((const __attribute__((address_space(1))) void*)g,
                                   (__attribute__((address_space(3))) void*)l, 16, 0, 0);
}

// swizzled LDS fragment read: tile rows = 64 shorts (128B), byte ^= (row&7)<<4
__device__ __forceinline__ const bf16x8* frag(const short* t, int row, int col) {
  int byt = (row << 7) + (col << 1);
  byt ^= (row & 7) << 4;
  return (const bf16x8*)((const char*)t + byt);
}

// ---------------- mask dtype detection (bool may arrive as u8 / i32 / f32) ----
__global__ __launch_bounds__(256) void detect_mask(const unsigned char* __restrict__ m,
                                                   int* __restrict__ flag) {
  __shared__ int f1, f23;
  if (threadIdx.x == 0) { f1 = 0; f23 = 0; }
  __syncthreads();
  int a = 0, b = 0;
  for (int i = threadIdx.x; i < 1024; i += 256) {
    if (m[i * 4 + 1]) a = 1;
    if (m[i * 4 + 2] | m[i * 4 + 3]) b = 1;
  }
  if (a) atomicOr(&f1, 1);
  if (b) atomicOr(&f23, 1);
  __syncthreads();
  if (threadIdx.x == 0) *flag = f1 ? 1 : (f23 ? 2 : 0);  // 1=u8, 2=f32, 0=i32
}

// ---------------- pack mask into bits: word w bit j = mask[w*32+j] -----------
__global__ __launch_bounds__(256) void pack_mask(const void* __restrict__ mask,
                                                 const int* __restrict__ flag,
                                                 unsigned* __restrict__ bits) {
  int wi = blockIdx.x * 256 + threadIdx.x;   // 0..131071
  int f = *flag;
  unsigned v = 0;
  if (f == 1) {
    const unsigned char* p = (const unsigned char*)mask + (size_t)wi * 32;
#pragma unroll
    for (int j = 0; j < 32; ++j) v |= (p[j] != 0 ? 1u : 0u) << j;
  } else if (f == 2) {
    const float* p = (const float*)mask + (size_t)wi * 32;
#pragma unroll
    for (int j = 0; j < 32; ++j) v |= (p[j] != 0.f ? 1u : 0u) << j;
  } else {
    const int* p = (const int*)mask + (size_t)wi * 32;
#pragma unroll
    for (int j = 0; j < 32; ++j) v |= (p[j] != 0 ? 1u : 0u) << j;
  }
  bits[wi] = v;
}

// ---------------- fp32 -> bf16 bulk convert (8 elems/thread) -----------------
__global__ __launch_bounds__(256) void conv_bf16(const float* __restrict__ in,
                                                 short* __restrict__ out, int n) {
  int i = (blockIdx.x * 256 + threadIdx.x) * 8;
  if (i >= n) return;
  f32x4 a = *(const f32x4*)&in[i];
  f32x4 b = *(const f32x4*)&in[i + 4];
  bf16x8 o;
#pragma unroll
  for (int j = 0; j < 4; ++j) o[j] = f2bf(a[j]);
#pragma unroll
  for (int j = 0; j < 4; ++j) o[4 + j] = f2bf(b[j]);
  *(bf16x8*)&out[i] = o;
}

// ---------------- transpose + convert: in fp32 [R][Cc] -> out bf16 [Cc][R] ---
__global__ __launch_bounds__(256) void transpose_conv(const float* __restrict__ in,
                                                      short* __restrict__ outp,
                                                      int R, int Cc) {
  __shared__ short tile[64][65];
  int c0 = blockIdx.x * 64, r0 = blockIdx.y * 64;
  int t = threadIdx.x;
  int tr = t >> 4;           // 0..15
  int tc = (t & 15) * 4;     // 0..60
  for (int rr = tr; rr < 64; rr += 16) {
    f32x4 v = *(const f32x4*)&in[(size_t)(r0 + rr) * Cc + c0 + tc];
#pragma unroll
    for (int j = 0; j < 4; ++j) tile[tc + j][rr] = f2bf(v[j]);
  }
  __syncthreads();
  for (int cc = tr; cc < 64; cc += 16) {
#pragma unroll
    for (int j = 0; j < 4; ++j)
      outp[(size_t)(c0 + cc) * R + r0 + tc + j] = tile[cc][tc + j];
  }
}

// ---------------- V transpose: qkv v-part [b][n][h][d] -> vt[b*h][d][n] ------
__global__ __launch_bounds__(256) void vtrans(const short* __restrict__ qkvb,
                                              short* __restrict__ vt) {
  __shared__ short t[64][72];
  int n0 = blockIdx.x * 64, bh = blockIdx.y;
  int b = bh / NHEAD, h = bh % NHEAD;
  int tid = threadIdx.x, r = tid >> 2, c0 = (tid & 3) * 16;
  const short* src = qkvb + (size_t)(b * NSEQ + n0 + r) * NQKV + 2 * CDIM + h * HD + c0;
  bf16x8 v0 = *(const bf16x8*)src;
  bf16x8 v1 = *(const bf16x8*)(src + 8);
  *(bf16x8*)&t[r][c0] = v0;
  *(bf16x8*)&t[r][c0 + 8] = v1;
  __syncthreads();
  bf16x8 o0, o1;
#pragma unroll
  for (int j = 0; j < 8; ++j) { o0[j] = t[c0 + j][r]; o1[j] = t[c0 + 8 + j][r]; }
  short* dst = vt + (size_t)(bh * HD + r) * NSEQ + n0 + c0;
  *(bf16x8*)&dst[0] = o0;
  *(bf16x8*)&dst[8] = o1;
}

// ---------------- bf16 GEMM: C[M,N] = A[M,K] * Bt[N,K]^T (+bias, f32 out) ----
// 128x128 tile, BK=32, 4 waves of 64x64; double-buffered LDS, counted vmcnt
template <bool F32OUT>
__global__ __launch_bounds__(256) void gemm_bt(const short* __restrict__ A,
                                               const short* __restrict__ Bt,
                                               void* __restrict__ Cout,
                                               const float* __restrict__ bias,
                                               int Mdim, int Ndim, int Kdim) {
  __shared__ short As[2][128 * 32];
  __shared__ short Bs[2][128 * 32];
  const int tid = threadIdx.x;
  const int lane = tid & 63;
  const int w = tid >> 6;
  const int wm = (w >> 1) * 64, wn = (w & 1) * 64;
  const int lr = lane & 15, lh = lane >> 4;
  const int m0 = blockIdx.y * 128, n0 = blockIdx.x * 128;

  f32x4 acc[4][4];
#pragma unroll
  for (int i = 0; i < 4; ++i)
#pragma unroll
    for (int j = 0; j < 4; ++j) acc[i][j] = (f32x4){0.f, 0.f, 0.f, 0.f};

  // staging: wave w covers rows w*32..w*32+31 (2 instr each for A,B)
  const int srow = w * 32 + (lane >> 2);
  const int scol = (lane & 3) * 8;
  const short* Ap = A + (size_t)(m0 + srow) * Kdim + scol;
  const short* Bp = Bt + (size_t)(n0 + srow) * Kdim + scol;
  const int l0 = (w * 32) * 32;
  const int l1 = (w * 32 + 16) * 32;

  auto tilecompute = [&](const short* Asb, const short* Bsb) {
    bf16x8 a[4], b[4];
#pragma unroll
    for (int i = 0; i < 4; ++i) a[i] = *(const bf16x8*)&Asb[(wm + i * 16 + lr) * 32 + lh * 8];
#pragma unroll
    for (int j = 0; j < 4; ++j) b[j] = *(const bf16x8*)&Bsb[(wn + j * 16 + lr) * 32 + lh * 8];
#pragma unroll
    for (int i = 0; i < 4; ++i)
#pragma unroll
      for (int j = 0; j < 4; ++j)
        acc[i][j] = __builtin_amdgcn_mfma_f32_16x16x32_bf16(a[i], b[j], acc[i][j], 0, 0, 0);
  };

  // prologue: stage tile 0 into buffer 0
  gload16(Ap, &As[0][l0]);
  gload16(Ap + (size_t)16 * Kdim, &As[0][l1]);
  gload16(Bp, &Bs[0][l0]);
  gload16(Bp + (size_t)16 * Kdim, &Bs[0][l1]);

  const int NT = Kdim >> 5;
  for (int t = 0; t < NT - 1; ++t) {
    const int cur = t & 1, nxt = cur ^ 1;
    const int k1 = (t + 1) << 5;
    gload16(Ap + k1, &As[nxt][l0]);
    gload16(Ap + (size_t)16 * Kdim + k1, &As[nxt][l1]);
    gload16(Bp + k1, &Bs[nxt][l0]);
    gload16(Bp + (size_t)16 * Kdim + k1, &Bs[nxt][l1]);
    asm volatile("s_waitcnt vmcnt(4)" ::: "memory");   // tile t landed; t+1 in flight
    __builtin_amdgcn_s_barrier();
    tilecompute(As[cur], Bs[cur]);
    __builtin_amdgcn_s_barrier();
  }
  asm volatile("s_waitcnt vmcnt(0)" ::: "memory");
  __builtin_amdgcn_s_barrier();
  tilecompute(As[(NT - 1) & 1], Bs[(NT - 1) & 1]);

#pragma unroll
  for (int i = 0; i < 4; ++i) {
    int mrowb = m0 + wm + i * 16 + lh * 4;
#pragma unroll
    for (int j = 0; j < 4; ++j) {
      int ncol = n0 + wn + j * 16 + lr;
#pragma unroll
      for (int r = 0; r < 4; ++r) {
        float v = acc[i][j][r];
        if (F32OUT)
          ((float*)Cout)[(size_t)(mrowb + r) * Ndim + ncol] = v + bias[ncol];
        else
          ((short*)Cout)[(size_t)(mrowb + r) * Ndim + ncol] = f2bf(v);
      }
    }
  }
}

// ---------------- flash attention, 32x32 MFMA, swapped QK^T ------------------
// 4 waves x 32 q-rows (QBLK=128), KVBLK=64; K/V double-buffered, counted vmcnt.
// Lane (q5 = lane&31, hi = lane>>5): q-row = w*32+q5; pair (l, l^32) shares a row.
// C-layout (m74/m101): C[col = lane&31][row = (reg&3)+8*(reg>>2)+4*hi].
__global__ __launch_bounds__(256) void flash_attn(const short* __restrict__ qkv,
                                                  const short* __restrict__ vtb,
                                                  const unsigned long long* __restrict__ mbits,
                                                  short* __restrict__ outp) {
  __shared__ short KB[2][64 * 64];
  __shared__ short VB[2][64 * 64];

  const int tid = threadIdx.x;
  const int lane = tid & 63;
  const int w = tid >> 6;
  const int q5 = lane & 31, hi = lane >> 5;
  const int q0 = blockIdx.x * 128;
  const int bh = blockIdx.y;
  const int b = bh / NHEAD, h = bh % NHEAD;
  const int qglob = q0 + w * 32 + q5;

  // staging geometry: per instr 8 rows x 128B; pre-swizzled source chunk
  const int srow = lane >> 3;                 // 0..7
  const int schunk = (lane & 7) ^ srow;       // inverse of read-side XOR swizzle

  // Q fragments (B-operand of QK^T): qf[ks] = Q[q][d = ks*16 + hi*8 .. +7], C2 folded
  const float C2 = 0.18033688f;               // 0.125 * log2(e)
  bf16x8 qf[4];
  {
    const short* qrow = qkv + (size_t)(b * NSEQ + qglob) * NQKV + h * HD;
#pragma unroll
    for (int ks = 0; ks < 4; ++ks) {
      bf16x8 v = *(const bf16x8*)(qrow + ks * 16 + hi * 8);
#pragma unroll
      for (int j = 0; j < 8; ++j) {
        union { unsigned u; float f; } c; c.u = ((unsigned)(unsigned short)v[j]) << 16;
        v[j] = f2bf(c.f * C2);
      }
      qf[ks] = v;
    }
  }
  asm volatile("" ::: "memory");

  const short* kbase = qkv + (size_t)(b * NSEQ + w * 16 + srow) * NQKV + CDIM + h * HD + schunk * 8;
  const short* vbase = vtb + (size_t)(bh * HD + w * 16 + srow) * NSEQ + schunk * 8;

  // stage tile 0
  gload16(kbase, &KB[0][(w * 16) * 64]);
  gload16(kbase + (size_t)8 * NQKV, &KB[0][(w * 16 + 8) * 64]);
  gload16(vbase, &VB[0][(w * 16) * 64]);
  gload16(vbase + (size_t)8 * NSEQ, &VB[0][(w * 16 + 8) * 64]);

  const unsigned long long* mrow = mbits + (size_t)qglob * (NSEQ / 64);
  unsigned long long mw = mrow[0];

  float m_r = -1e30f, l_r = 0.f;
  f32x16 o[2];
#pragma unroll
  for (int dt = 0; dt < 2; ++dt)
#pragma unroll
    for (int r = 0; r < 16; ++r) o[dt][r] = 0.f;

  auto compute = [&](const short* Kb, const short* Vb, unsigned long long mwv) {
    // S^T: st[kvt][reg] = S[q][kv = kvt*32 + (reg&3)+8*(reg>>2)+4*hi] (exp2 domain)
    f32x16 st[2];
#pragma unroll
    for (int kvt = 0; kvt < 2; ++kvt) {
      f32x16 z;
#pragma unroll
      for (int r = 0; r < 16; ++r) z[r] = 0.f;
#pragma unroll
      for (int ks = 0; ks < 4; ++ks)
        z = __builtin_amdgcn_mfma_f32_32x32x16_bf16(
            *frag(Kb, kvt * 32 + q5, ks * 16 + hi * 8), qf[ks], z, 0, 0, 0);
      st[kvt] = z;
    }

    // mask: bit kv5 of word kvt; pre-shift by 4*hi so per-reg position is constant
    unsigned msk0 = ((unsigned)mwv) >> (hi * 4);
    unsigned msk1 = ((unsigned)(mwv >> 32)) >> (hi * 4);
    float pm = -3e38f;
#pragma unroll
    for (int kvt = 0; kvt < 2; ++kvt) {
      unsigned mk = kvt ? msk1 : msk0;
#pragma unroll
      for (int r = 0; r < 16; ++r) {
        const int pos = (r & 3) + 8 * (r >> 2);
        float sv = st[kvt][r];
        sv = ((mk >> pos) & 1u) ? -3e38f : sv;
        st[kvt][r] = sv;
        pm = fmaxf(pm, sv);
      }
    }
    pm = fmaxf(pm, __shfl_xor(pm, 32, 64));

    if (__any(pm > m_r + 8.f)) {        // defer-max
      float nm = fmaxf(m_r, pm);
      float al = exp2a(m_r - nm);
      m_r = nm;
      l_r *= al;
#pragma unroll
      for (int dt = 0; dt < 2; ++dt)
#pragma unroll
        for (int r = 0; r < 16; ++r) o[dt][r] *= al;
    }

    float rs0 = 0.f, rs1 = 0.f;
#pragma unroll
    for (int r = 0; r < 16; ++r) {
      float e0 = exp2a(st[0][r] - m_r);
      float e1 = exp2a(st[1][r] - m_r);
      st[0][r] = e0; st[1][r] = e1;
      rs0 += e0; rs1 += e1;
    }
    float rs = rs0 + rs1;
    rs += __shfl_xor(rs, 32, 64);
    l_r += rs;

    // pack P to bf16, pair-exchange (lane <-> lane^32) to build PV B-fragments:
    // pb[ks] = P[q][kv = ks*16 + hi*8 + j], j=0..7
    unsigned pbw[4][4];
#pragma unroll
    for (int ks = 0; ks < 4; ++ks) {
      const int kvt = ks >> 1;
      const int Ra = (ks & 1) * 8;     // regs feeding hi0-dest
      const int Rb = Ra + 4;           // regs feeding hi1-dest
      unsigned wa0 = cvtpk(st[kvt][Ra],     st[kvt][Ra + 1]);
      unsigned wa1 = cvtpk(st[kvt][Ra + 2], st[kvt][Ra + 3]);
      unsigned wb0 = cvtpk(st[kvt][Rb],     st[kvt][Rb + 1]);
      unsigned wb1 = cvtpk(st[kvt][Rb + 2], st[kvt][Rb + 3]);
      unsigned s0 = hi ? wa0 : wb0;    // what the partner needs
      unsigned s1 = hi ? wa1 : wb1;
      unsigned r0 = __shfl_xor(s0, 32, 64);
      unsigned r1 = __shfl_xor(s1, 32, 64);
      pbw[ks][0] = hi ? r0 : wa0;
      pbw[ks][1] = hi ? r1 : wa1;
      pbw[ks][2] = hi ? wb0 : r0;
      pbw[ks][3] = hi ? wb1 : r1;
    }

    // O^T += V^T · P^T
#pragma unroll
    for (int dt = 0; dt < 2; ++dt)
#pragma unroll
      for (int ks = 0; ks < 4; ++ks) {
        union { unsigned u[4]; bf16x8 v; } pu;
        pu.u[0] = pbw[ks][0]; pu.u[1] = pbw[ks][1];
        pu.u[2] = pbw[ks][2]; pu.u[3] = pbw[ks][3];
        o[dt] = __builtin_amdgcn_mfma_f32_32x32x16_bf16(
            *frag(Vb, dt * 32 + q5, ks * 16 + hi * 8), pu.v, o[dt], 0, 0, 0);
      }
  };

  for (int t = 0; t < 31; ++t) {
    const int cur = t & 1, nxt = cur ^ 1;
    {
      const short* kb = kbase + (size_t)(t + 1) * 64 * NQKV;
      gload16(kb, &KB[nxt][(w * 16) * 64]);
      gload16(kb + (size_t)8 * NQKV, &KB[nxt][(w * 16 + 8) * 64]);
      const short* vb = vbase + (t + 1) * 64;
      gload16(vb, &VB[nxt][(w * 16) * 64]);
      gload16(vb + (size_t)8 * NSEQ, &VB[nxt][(w * 16 + 8) * 64]);
    }
    asm volatile("s_waitcnt vmcnt(4)" ::: "memory");   // tile t (+mask t) landed
    unsigned long long mw_next = mrow[t + 1];
    __builtin_amdgcn_s_barrier();
    compute(KB[cur], VB[cur], mw);
    mw = mw_next;
    __builtin_amdgcn_s_barrier();
  }
  asm volatile("s_waitcnt vmcnt(0)" ::: "memory");
  __builtin_amdgcn_s_barrier();
  compute(KB[1], VB[1], mw);

  // epilogue: o[dt][reg] = O[q][d = dt*32 + (reg&3) + 8*(reg>>2) + 4*hi]
  const float inv = 1.f / l_r;
  short* orow = outp + (size_t)(b * NSEQ + qglob) * CDIM + h * HD;
#pragma unroll
  for (int dt = 0; dt < 2; ++dt)
#pragma unroll
    for (int g = 0; g < 4; ++g) {
      short4v sv;
#pragma unroll
      for (int r = 0; r < 4; ++r) sv[r] = f2bf(o[dt][g * 4 + r] * inv);
      *(short4v*)&orow[dt * 32 + g * 8 + hi * 4] = sv;
    }
}

// ---------------- launch --------------------------------------------------
extern "C" void kernel_launch(void* const* d_in, const int* in_sizes, int n_in,
                              void* d_out, int out_size, void* d_ws, size_t ws_size,
                              hipStream_t stream) {
  const float* x      = (const float*)d_in[0];
  const void*  mask   = d_in[1];
  const float* w_qkv  = (const float*)d_in[2];
  const float* w_proj = (const float*)d_in[3];
  const float* b_proj = (const float*)d_in[4];
  float* outp = (float*)d_out;
  char* ws = (char*)d_ws;

  int*      flag   = (int*)(ws + 0);
  unsigned* mbits  = (unsigned*)(ws + 1024);                 // 524288 B
  short*    xb     = (short*)(ws + 525312);                  // 25165824 B (freed after QKV GEMM)
  short*    wqkvT  = (short*)(ws + 25691136);                // 3538944 B
  short*    wprojT = (short*)(ws + 29230080);                // 1179648 B
  short*    qkvb   = (short*)(ws + 30409728);                // 37748736 B
  short*    attnb  = (short*)(ws + 68158464);                // 12582912 B
  short*    vtb    = xb;                                     // reuse xb: 12582912 B needed

  detect_mask<<<1, 256, 0, stream>>>((const unsigned char*)mask, flag);
  pack_mask<<<512, 256, 0, stream>>>(mask, flag, mbits);
  conv_bf16<<<(MTOT * CDIM) / 2048, 256, 0, stream>>>(x, xb, MTOT * CDIM);
  transpose_conv<<<dim3(NQKV / 64, CDIM / 64), 256, 0, stream>>>(w_qkv, wqkvT, CDIM, NQKV);
  transpose_conv<<<dim3(CDIM / 64, CDIM / 64), 256, 0, stream>>>(w_proj, wprojT, CDIM, CDIM);
  gemm_bt<false><<<dim3(NQKV / 128, MTOT / 128), 256, 0, stream>>>(xb, wqkvT, qkvb, nullptr,
                                                                   MTOT, NQKV, CDIM);
  vtrans<<<dim3(NSEQ / 64, NBATCH * NHEAD), 256, 0, stream>>>(qkvb, vtb);
  flash_attn<<<dim3(NSEQ / 128, NBATCH * NHEAD), 256, 0, stream>>>(
      qkvb, vtb, (const unsigned long long*)mbits, attnb);
  gemm_bt<true><<<dim3(CDIM / 128, MTOT / 128), 256, 0, stream>>>(attnb, wprojT, outp, b_proj,
                                                                  MTOT, CDIM, CDIM);
}